// Round 7
// baseline (209.349 us; speedup 1.0000x reference)
//
#include <hip/hip_runtime.h>
#include <hip/hip_bf16.h>
#include <math.h>

#define HW 9216      // 96*96
#define C2 64
#define NCHUNK 48    // j-split factor (chunk rounded to mult of 32; 48*192 == 9216)
#define JTILE 32     // j-tile per lane = 32 asm-held accumulators
#define EPSN 1e-8f

// 32 v_fmac_f32: acc_k += s(36+k) * av   (one SGPR + one VGPR source each)
#define FMAS(AV) \
  "v_fmac_f32 %[a0], s36, %[" AV "]\n\t"  "v_fmac_f32 %[a1], s37, %[" AV "]\n\t" \
  "v_fmac_f32 %[a2], s38, %[" AV "]\n\t"  "v_fmac_f32 %[a3], s39, %[" AV "]\n\t" \
  "v_fmac_f32 %[a4], s40, %[" AV "]\n\t"  "v_fmac_f32 %[a5], s41, %[" AV "]\n\t" \
  "v_fmac_f32 %[a6], s42, %[" AV "]\n\t"  "v_fmac_f32 %[a7], s43, %[" AV "]\n\t" \
  "v_fmac_f32 %[a8], s44, %[" AV "]\n\t"  "v_fmac_f32 %[a9], s45, %[" AV "]\n\t" \
  "v_fmac_f32 %[a10], s46, %[" AV "]\n\t" "v_fmac_f32 %[a11], s47, %[" AV "]\n\t" \
  "v_fmac_f32 %[a12], s48, %[" AV "]\n\t" "v_fmac_f32 %[a13], s49, %[" AV "]\n\t" \
  "v_fmac_f32 %[a14], s50, %[" AV "]\n\t" "v_fmac_f32 %[a15], s51, %[" AV "]\n\t" \
  "v_fmac_f32 %[a16], s52, %[" AV "]\n\t" "v_fmac_f32 %[a17], s53, %[" AV "]\n\t" \
  "v_fmac_f32 %[a18], s54, %[" AV "]\n\t" "v_fmac_f32 %[a19], s55, %[" AV "]\n\t" \
  "v_fmac_f32 %[a20], s56, %[" AV "]\n\t" "v_fmac_f32 %[a21], s57, %[" AV "]\n\t" \
  "v_fmac_f32 %[a22], s58, %[" AV "]\n\t" "v_fmac_f32 %[a23], s59, %[" AV "]\n\t" \
  "v_fmac_f32 %[a24], s60, %[" AV "]\n\t" "v_fmac_f32 %[a25], s61, %[" AV "]\n\t" \
  "v_fmac_f32 %[a26], s62, %[" AV "]\n\t" "v_fmac_f32 %[a27], s63, %[" AV "]\n\t" \
  "v_fmac_f32 %[a28], s64, %[" AV "]\n\t" "v_fmac_f32 %[a29], s65, %[" AV "]\n\t" \
  "v_fmac_f32 %[a30], s66, %[" AV "]\n\t" "v_fmac_f32 %[a31], s67, %[" AV "]\n\t"

// ---------------- kernel 1: compaction (256 threads, shuffle scan) --------
__global__ void compact_kernel(const int* __restrict__ mask, int* __restrict__ ilist,
                               int* __restrict__ jlist, int* __restrict__ counts) {
    int t = threadIdx.x;                 // 0..255, each owns 36 consecutive positions
    int base = t * 36;
    unsigned long long fl = 0ull; int cnt = 0;
#pragma unroll
    for (int k = 0; k < 36; k++) {
        int f = (mask[base + k] >= 1) ? 1 : 0;
        fl |= (unsigned long long)f << k;
        cnt += f;
    }
    int lane = t & 63, wave = t >> 6;
    int v = cnt;
#pragma unroll
    for (int off = 1; off < 64; off <<= 1) {
        int u = __shfl_up(v, off, 64);
        if (lane >= off) v += u;
    }
    __shared__ int wsum[4];
    if (lane == 63) wsum[wave] = v;
    __syncthreads();
    int woff = 0;
#pragma unroll
    for (int w = 0; w < 4; w++) if (w < wave) woff += wsum[w];
    int incl = v + woff;
    int excl = incl - cnt;
    int posF = excl, posU = base - excl;
#pragma unroll
    for (int k = 0; k < 36; k++) {
        int p = base + k;
        if ((fl >> k) & 1ull) ilist[posF++] = p; else jlist[posU++] = p;
    }
    if (t == 255) { counts[0] = incl; counts[1] = HW - incl; }
}

// ---------------- kernel 2: build transposed normalized B + zero amax -----
__global__ void buildb_kernel(const float* __restrict__ x, const int* __restrict__ jlist,
                              const int* __restrict__ counts, float* __restrict__ bmatT,
                              unsigned long long* __restrict__ amax) {
    int t = blockIdx.x * blockDim.x + threadIdx.x;   // 0 .. 2*HW-1
    if (t >= 2 * HW) return;
    amax[t] = 0ull;                                  // ws is poisoned 0xAA pre-launch
    int b = t / HW, p = t - b * HW;
    int nj = counts[1];
    float v[C2];
    if (p < nj) {
        int j = jlist[p];
        const float* xl = x + (size_t)(b * 128 + 64) * HW + j;
        float ss = 0.f;
#pragma unroll
        for (int c = 0; c < C2; c++) { float w = xl[(size_t)c * HW]; v[c] = w; ss = fmaf(w, w, ss); }
        float inv = 1.0f / fmaxf(sqrtf(ss), EPSN);
#pragma unroll
        for (int c = 0; c < C2; c++) v[c] *= inv;
    } else {
#pragma unroll
        for (int c = 0; c < C2; c++) v[c] = 0.f;
    }
    float* d = bmatT + (size_t)b * C2 * HW + p;
#pragma unroll
    for (int c = 0; c < C2; c++) d[(size_t)c * HW] = v[c];
}

// ordered-float mapping: monotone bijection float -> uint32 under unsigned compare
__device__ __forceinline__ unsigned int ordf(float f) {
    unsigned int u = __float_as_uint(f);
    return (u & 0x80000000u) ? ~u : (u | 0x80000000u);
}

// ---------------- kernel 3: main argmax-"GEMM" (hand-asm inner loop) ------
// The entire c-loop lives in ONE asm volatile block: 32 "+v" accumulators
// (regalloc must keep all live; mid-end cannot see inside), b-row via
// explicit uniform s_load_dwordx16 x2 (lgkmcnt(0) waits - SMEM is OOO),
// per-lane a via saddr-form global_load, double-buffered with in-order
// vmcnt(1) waits. 31 iters x 2 phases + 2 peeled tail phases (rows 62,63).
// First-max tie-break: ascending jb, ascending k, strict >, packed-u64
// atomicMax (key = ord(val)<<32 | ~jj).
__global__ __launch_bounds__(256, 8) void argmax_kernel(
    const float* __restrict__ x, const float* __restrict__ bmatT,
    const int* __restrict__ ilist, const int* __restrict__ counts,
    unsigned long long* __restrict__ amax)
{
    int b = blockIdx.z;
    int s = blockIdx.y;
    int ci = blockIdx.x * 256 + threadIdx.x;
    int ni = counts[0], nj = counts[1];
    if (blockIdx.x * 256 >= ni) return;              // dead block (all-exit if ni==0)
    bool valid = (ci < ni);
    int i = ilist[valid ? ci : ni - 1];              // clamp tail lanes
    const float* sb = x + (size_t)(b * 128 + 64) * HW;   // uniform a-base (sgpr pair)
    const float* bbase = bmatT + (size_t)b * C2 * HW;
    int chunk = (((nj + NCHUNK - 1) / NCHUNK) + 31) & ~31;   // mult of 32 (<=192)
    int j0 = s * chunk;
    int j1 = min(j0 + chunk, nj);
    float best = -INFINITY; int bestjj = -1;
    for (int jb = j0; jb < j1; jb += JTILE) {
        const float* bp = bbase + jb;                // uniform, 128B-aligned
        unsigned vo = (unsigned)(i * 4);             // per-lane byte offset vs sb
        unsigned cnt;
        float av0, av1;
        float a0=0.f,a1=0.f,a2=0.f,a3=0.f,a4=0.f,a5=0.f,a6=0.f,a7=0.f,
              a8=0.f,a9=0.f,a10=0.f,a11=0.f,a12=0.f,a13=0.f,a14=0.f,a15=0.f,
              a16=0.f,a17=0.f,a18=0.f,a19=0.f,a20=0.f,a21=0.f,a22=0.f,a23=0.f,
              a24=0.f,a25=0.f,a26=0.f,a27=0.f,a28=0.f,a29=0.f,a30=0.f,a31=0.f;
        asm volatile(
            // init: b base -> s[34:35]; prime a double-buffer (rows 0,1)
            "s_mov_b64 s[34:35], %[bp]\n\t"
            "global_load_dword %[av0], %[vo], %[sb]\n\t"
            "v_add_u32 %[vo], 0x9000, %[vo]\n\t"
            "global_load_dword %[av1], %[vo], %[sb]\n\t"
            "s_mov_b32 %[cnt], 31\n\t"
            "L%=:\n\t"
            // phase A: row c (even): load b row, wait, 32 fmac, prefetch a(c+2)
            "s_load_dwordx16 s[36:51], s[34:35], 0x0\n\t"
            "s_load_dwordx16 s[52:67], s[34:35], 0x40\n\t"
            "s_add_u32 s34, s34, 0x9000\n\t"
            "s_addc_u32 s35, s35, 0\n\t"
            "v_add_u32 %[vo], 0x9000, %[vo]\n\t"
            "s_waitcnt lgkmcnt(0) vmcnt(1)\n\t"
            FMAS("av0")
            "global_load_dword %[av0], %[vo], %[sb]\n\t"
            // phase B: row c+1 (odd)
            "s_load_dwordx16 s[36:51], s[34:35], 0x0\n\t"
            "s_load_dwordx16 s[52:67], s[34:35], 0x40\n\t"
            "s_add_u32 s34, s34, 0x9000\n\t"
            "s_addc_u32 s35, s35, 0\n\t"
            "v_add_u32 %[vo], 0x9000, %[vo]\n\t"
            "s_waitcnt lgkmcnt(0) vmcnt(1)\n\t"
            FMAS("av1")
            "global_load_dword %[av1], %[vo], %[sb]\n\t"
            "s_sub_u32 %[cnt], %[cnt], 1\n\t"
            "s_cmp_lg_u32 %[cnt], 0\n\t"
            "s_cbranch_scc1 L%=\n\t"
            // tail: row 62 (av0 pending), row 63 (av1 pending)
            "s_load_dwordx16 s[36:51], s[34:35], 0x0\n\t"
            "s_load_dwordx16 s[52:67], s[34:35], 0x40\n\t"
            "s_add_u32 s34, s34, 0x9000\n\t"
            "s_addc_u32 s35, s35, 0\n\t"
            "s_waitcnt lgkmcnt(0) vmcnt(1)\n\t"
            FMAS("av0")
            "s_load_dwordx16 s[36:51], s[34:35], 0x0\n\t"
            "s_load_dwordx16 s[52:67], s[34:35], 0x40\n\t"
            "s_waitcnt lgkmcnt(0) vmcnt(0)\n\t"
            FMAS("av1")
            : [a0]"+v"(a0),[a1]"+v"(a1),[a2]"+v"(a2),[a3]"+v"(a3),
              [a4]"+v"(a4),[a5]"+v"(a5),[a6]"+v"(a6),[a7]"+v"(a7),
              [a8]"+v"(a8),[a9]"+v"(a9),[a10]"+v"(a10),[a11]"+v"(a11),
              [a12]"+v"(a12),[a13]"+v"(a13),[a14]"+v"(a14),[a15]"+v"(a15),
              [a16]"+v"(a16),[a17]"+v"(a17),[a18]"+v"(a18),[a19]"+v"(a19),
              [a20]"+v"(a20),[a21]"+v"(a21),[a22]"+v"(a22),[a23]"+v"(a23),
              [a24]"+v"(a24),[a25]"+v"(a25),[a26]"+v"(a26),[a27]"+v"(a27),
              [a28]"+v"(a28),[a29]"+v"(a29),[a30]"+v"(a30),[a31]"+v"(a31),
              [vo]"+v"(vo), [cnt]"=&s"(cnt), [av0]"=&v"(av0), [av1]"=&v"(av1)
            : [bp]"s"(bp), [sb]"s"(sb)
            : "s34","s35","s36","s37","s38","s39","s40","s41","s42","s43",
              "s44","s45","s46","s47","s48","s49","s50","s51","s52","s53",
              "s54","s55","s56","s57","s58","s59","s60","s61","s62","s63",
              "s64","s65","s66","s67","scc","memory");
        int lim = j1 - jb;                            // tail guard (padded cols are zeros)
#define SELK(k) if (k < lim && a##k > best) { best = a##k; bestjj = jb + k; }
        SELK(0) SELK(1) SELK(2) SELK(3) SELK(4) SELK(5) SELK(6) SELK(7)
        SELK(8) SELK(9) SELK(10) SELK(11) SELK(12) SELK(13) SELK(14) SELK(15)
        SELK(16) SELK(17) SELK(18) SELK(19) SELK(20) SELK(21) SELK(22) SELK(23)
        SELK(24) SELK(25) SELK(26) SELK(27) SELK(28) SELK(29) SELK(30) SELK(31)
    }
    if (valid && bestjj >= 0) {
        unsigned long long key = ((unsigned long long)ordf(best) << 32) |
                                 (unsigned long long)(~(unsigned int)bestjj);
        atomicMax(&amax[(size_t)b * HW + ilist[ci]], key);   // indexed by ORIGINAL position
    }
}

// ---------------- kernel 4: fused epilogue (copy + decode + gather) -------
__global__ void epilogue_kernel(const float4* __restrict__ x4, const float* __restrict__ x,
                                const int* __restrict__ mask,
                                const unsigned long long* __restrict__ amax,
                                const int* __restrict__ jlist, float4* __restrict__ out4) {
    const int q = HW / 4;                            // 2304
    int t = blockIdx.x * blockDim.x + threadIdx.x;   // 0 .. 2*192*q-1
    if (t >= 2 * 192 * q) return;
    int pos4 = t % q;
    int c = (t / q) % 192;
    int b = t / (192 * q);
    if (c < 128) {
        out4[t] = x4[((size_t)b * 128 + c) * q + pos4];
    } else {
        float4 v = make_float4(0.f, 0.f, 0.f, 0.f);
        float* vp = &v.x;
        int pos = pos4 * 4;
        const float* xf = x + (size_t)(b * 128 + (c - 128)) * HW;
#pragma unroll
        for (int k = 0; k < 4; k++) {
            int p = pos + k;
            if (mask[p] >= 1) {
                unsigned long long key = amax[(size_t)b * HW + p];
                int j = 0;                           // nj==0 -> argmax of all-NEG row = 0
                if (key != 0ull) j = jlist[(int)(~(unsigned int)key)];
                vp[k] = xf[j];
            }
        }
        out4[t] = v;
    }
}

extern "C" void kernel_launch(void* const* d_in, const int* in_sizes, int n_in,
                              void* d_out, int out_size, void* d_ws, size_t ws_size,
                              hipStream_t stream) {
    const float* x = (const float*)d_in[0];
    const int* mask = (const int*)d_in[1];
    float4* out4 = (float4*)d_out;

    // workspace layout: counts(0) | ilist(128) | jlist(36992) | amax(73856)
    //                   | bmatT(221312, 128B-aligned)
    char* ws = (char*)d_ws;
    int*   counts = (int*)ws;
    int*   ilist  = (int*)(ws + 128);
    int*   jlist  = (int*)(ws + 128 + 36864);
    unsigned long long* amax = (unsigned long long*)(ws + 128 + 2 * 36864);
    float* bmatT  = (float*)(ws + 128 + 2 * 36864 + 147456);

    compact_kernel<<<1, 256, 0, stream>>>(mask, ilist, jlist, counts);
    buildb_kernel<<<(2 * HW + 255) / 256, 256, 0, stream>>>(x, jlist, counts, bmatT, amax);
    {
        dim3 grid((HW + 255) / 256, NCHUNK, 2);
        argmax_kernel<<<grid, 256, 0, stream>>>(x, bmatT, ilist, counts, amax);
    }
    {
        int n = 2 * 192 * (HW / 4);
        epilogue_kernel<<<(n + 255) / 256, 256, 0, stream>>>((const float4*)x, x, mask, amax, jlist, out4);
    }
}

// Round 8
// 169.171 us; speedup vs baseline: 1.2375x; 1.2375x over previous
//
#include <hip/hip_runtime.h>
#include <hip/hip_bf16.h>
#include <math.h>

#define HW 9216      // 96*96
#define C2 64
#define NJC 8        // j-chunk count (grid.y)
#define EPSN 1e-8f

typedef float v4 __attribute__((ext_vector_type(4)));

// ---------------- kernel 1: compaction (256 threads, shuffle scan) --------
// ilist = positions with mask>=1 (flagged i), jlist = positions with mask<1
__global__ void compact_kernel(const int* __restrict__ mask, int* __restrict__ ilist,
                               int* __restrict__ jlist, int* __restrict__ counts) {
    int t = threadIdx.x;                 // 0..255, each owns 36 consecutive positions
    int base = t * 36;
    unsigned long long fl = 0ull; int cnt = 0;
#pragma unroll
    for (int k = 0; k < 36; k++) {
        int f = (mask[base + k] >= 1) ? 1 : 0;
        fl |= (unsigned long long)f << k;
        cnt += f;
    }
    int lane = t & 63, wave = t >> 6;
    int v = cnt;
#pragma unroll
    for (int off = 1; off < 64; off <<= 1) {
        int u = __shfl_up(v, off, 64);
        if (lane >= off) v += u;
    }
    __shared__ int wsum[4];
    if (lane == 63) wsum[wave] = v;
    __syncthreads();
    int woff = 0;
#pragma unroll
    for (int w = 0; w < 4; w++) if (w < wave) woff += wsum[w];
    int incl = v + woff;
    int excl = incl - cnt;
    int posF = excl, posU = base - excl;
#pragma unroll
    for (int k = 0; k < 36; k++) {
        int p = base + k;
        if ((fl >> k) & 1ull) ilist[posF++] = p; else jlist[posU++] = p;
    }
    if (t == 255) { counts[0] = incl; counts[1] = HW - incl; }
}

// ---------------- kernel 2: build transposed compacted A and B ------------
// amatT[b][c][ci] = lat[b][c][ilist[ci]]                    (unnormalized)
// bmatT[b][c][jj] = lat[b][c][jlist[jj]] / max(||lat_j||,eps)
// zero-padded to HW columns so GEMM tiles read benign zeros. Also zeroes amax.
__global__ void buildab_kernel(const float* __restrict__ x, const int* __restrict__ ilist,
                               const int* __restrict__ jlist, const int* __restrict__ counts,
                               float* __restrict__ amatT, float* __restrict__ bmatT,
                               unsigned long long* __restrict__ amax) {
    int t = blockIdx.x * blockDim.x + threadIdx.x;   // 0 .. 4*HW-1
    if (t >= 4 * HW) return;
    if (t < 2 * HW) amax[t] = 0ull;                  // ws is poisoned 0xAA pre-launch
    int kind = t / (2 * HW);                         // 0 = A, 1 = B
    int r = t - kind * 2 * HW;
    int b = r / HW, p = r - b * HW;
    int n = kind ? counts[1] : counts[0];
    float v[C2];
    if (p < n) {
        int src = kind ? jlist[p] : ilist[p];
        const float* xl = x + (size_t)(b * 128 + 64) * HW + src;
        float ss = 0.f;
#pragma unroll
        for (int c = 0; c < C2; c++) { float w = xl[(size_t)c * HW]; v[c] = w; ss = fmaf(w, w, ss); }
        if (kind) {
            float inv = 1.0f / fmaxf(sqrtf(ss), EPSN);
#pragma unroll
            for (int c = 0; c < C2; c++) v[c] *= inv;
        }
    } else {
#pragma unroll
        for (int c = 0; c < C2; c++) v[c] = 0.f;
    }
    float* d = (kind ? bmatT : amatT) + (size_t)b * C2 * HW + p;
#pragma unroll
    for (int c = 0; c < C2; c++) d[(size_t)c * HW] = v[c];
}

// ordered-float mapping: monotone bijection float -> uint32 under unsigned compare
__device__ __forceinline__ unsigned int ordf(float f) {
    unsigned int u = __float_as_uint(f);
    return (u & 0x80000000u) ? ~u : (u | 0x80000000u);
}

// ---------------- kernel 3: LDS-tiled fp32 GEMM + argmax ------------------
// Block (256 thr) computes a 64i x 64j tile: 16x16 lane grid, each lane owns
// a 4x4 micro-tile (16 accs + 8 operands ~ 35 VGPR -> fits the 8-wave budget,
// no remat incentive). Per k: 2x ds_read_b128 + 16 v_fmac (16/18 slots FMA).
// A-tile staged once; B-tiles streamed over this block's j-chunk.
// Argmax: per-lane best over its rows (ascending j, strict >), block-reduce
// via LDS keys, one packed-u64 atomicMax per live row (key=ord(v)<<32|~j).
__global__ __launch_bounds__(256, 8) void gemm_argmax_kernel(
    const float* __restrict__ amatT, const float* __restrict__ bmatT,
    const int* __restrict__ ilist, const int* __restrict__ counts,
    unsigned long long* __restrict__ amax)
{
    __shared__ float As[64][64];                     // 16 KB  [c][i]
    __shared__ float Bs[64][64];                     // 16 KB  [c][j]
    __shared__ unsigned long long keys[64][16];      // 8 KB   [row][j4]
    int b = blockIdx.z;
    int sc = blockIdx.y;
    int i0 = blockIdx.x * 64;
    int ni = counts[0], nj = counts[1];
    if (i0 >= ni) return;                            // uniform dead-block exit
    int t = threadIdx.x;
    int i4 = t & 15, j4 = t >> 4;
    // stage A once (coalesced float4; amatT zero-padded past ni)
    const float* Ab = amatT + (size_t)b * C2 * HW;
#pragma unroll
    for (int q = 0; q < 4; q++) {
        int idx = q * 256 + t;                       // 0..1023 float4 slots
        int c = idx >> 4, col4 = (idx & 15) * 4;
        *(v4*)&As[c][col4] = *(const v4*)&Ab[(size_t)c * HW + i0 + col4];
    }
    // this block's j-tile range
    int jt_total = (nj + 63) >> 6;
    int tpc = (jt_total + NJC - 1) / NJC;
    int t0 = sc * tpc, t1 = min(t0 + tpc, jt_total);
    const float* Bb = bmatT + (size_t)b * C2 * HW;
    float best0 = -INFINITY, best1 = -INFINITY, best2 = -INFINITY, best3 = -INFINITY;
    int bj0 = -1, bj1 = -1, bj2 = -1, bj3 = -1;
    for (int tt = t0; tt < t1; ++tt) {
        int j0 = tt * 64;
        __syncthreads();                             // Bs readers from prev iter done (also covers As stage on iter 0)
#pragma unroll
        for (int q = 0; q < 4; q++) {
            int idx = q * 256 + t;
            int c = idx >> 4, col4 = (idx & 15) * 4;
            *(v4*)&Bs[c][col4] = *(const v4*)&Bb[(size_t)c * HW + j0 + col4];
        }
        __syncthreads();
        v4 acc0 = {0.f,0.f,0.f,0.f}, acc1 = {0.f,0.f,0.f,0.f};
        v4 acc2 = {0.f,0.f,0.f,0.f}, acc3 = {0.f,0.f,0.f,0.f};
#pragma unroll 8
        for (int c = 0; c < 64; ++c) {
            v4 av = *(const v4*)&As[c][i4 * 4];      // rows 4*i4..+3 (broadcast x16 lanes)
            v4 bv = *(const v4*)&Bs[c][j4 * 4];      // cols 4*j4..+3
            acc0 += bv * av.x;
            acc1 += bv * av.y;
            acc2 += bv * av.z;
            acc3 += bv * av.w;
        }
        // selection over lane's 4 cols, ascending j, strict > (first-max)
        int jb = j0 + j4 * 4;
#define SEL(R) { \
        if (jb + 0 < nj && acc##R.x > best##R) { best##R = acc##R.x; bj##R = jb + 0; } \
        if (jb + 1 < nj && acc##R.y > best##R) { best##R = acc##R.y; bj##R = jb + 1; } \
        if (jb + 2 < nj && acc##R.z > best##R) { best##R = acc##R.z; bj##R = jb + 2; } \
        if (jb + 3 < nj && acc##R.w > best##R) { best##R = acc##R.w; bj##R = jb + 3; } }
        SEL(0) SEL(1) SEL(2) SEL(3)
#undef SEL
    }
    // block-level reduce: keys[row][j4], then max over 16 j4 groups per row
#define KEY(B, J) ((J) >= 0 ? (((unsigned long long)ordf(B) << 32) | (unsigned long long)(~(unsigned)(J))) : 0ull)
    keys[i4 * 4 + 0][j4] = KEY(best0, bj0);
    keys[i4 * 4 + 1][j4] = KEY(best1, bj1);
    keys[i4 * 4 + 2][j4] = KEY(best2, bj2);
    keys[i4 * 4 + 3][j4] = KEY(best3, bj3);
#undef KEY
    __syncthreads();
    if (t < 64) {
        unsigned long long m = 0ull;
#pragma unroll
        for (int g = 0; g < 16; g++) { unsigned long long k = keys[t][g]; if (k > m) m = k; }
        int i = i0 + t;
        if (m != 0ull && i < ni)
            atomicMax(&amax[(size_t)b * HW + ilist[i]], m);  // keyed by ORIGINAL position
    }
}

// ---------------- kernel 4: fused epilogue (copy + decode + gather) -------
// out channels [0,128): passthrough copy of x (float4).
// out channels [128,192): shift = former at argmax j (0 where !flag).
__global__ void epilogue_kernel(const float4* __restrict__ x4, const float* __restrict__ x,
                                const int* __restrict__ mask,
                                const unsigned long long* __restrict__ amax,
                                const int* __restrict__ jlist, float4* __restrict__ out4) {
    const int q = HW / 4;                            // 2304
    int t = blockIdx.x * blockDim.x + threadIdx.x;   // 0 .. 2*192*q-1
    if (t >= 2 * 192 * q) return;
    int pos4 = t % q;
    int c = (t / q) % 192;
    int b = t / (192 * q);
    if (c < 128) {
        out4[t] = x4[((size_t)b * 128 + c) * q + pos4];
    } else {
        float4 v = make_float4(0.f, 0.f, 0.f, 0.f);
        float* vp = &v.x;
        int pos = pos4 * 4;
        const float* xf = x + (size_t)(b * 128 + (c - 128)) * HW;
#pragma unroll
        for (int k = 0; k < 4; k++) {
            int p = pos + k;
            if (mask[p] >= 1) {
                unsigned long long key = amax[(size_t)b * HW + p];
                int j = 0;                           // nj==0 -> argmax of all-NEG row = 0
                if (key != 0ull) j = jlist[(int)(~(unsigned int)key)];
                vp[k] = xf[j];
            }
        }
        out4[t] = v;
    }
}

extern "C" void kernel_launch(void* const* d_in, const int* in_sizes, int n_in,
                              void* d_out, int out_size, void* d_ws, size_t ws_size,
                              hipStream_t stream) {
    const float* x = (const float*)d_in[0];
    const int* mask = (const int*)d_in[1];
    float4* out4 = (float4*)d_out;

    // workspace: counts(0) | ilist(128) | jlist(+36864) | amax(+36864)
    //            | amatT(+147456) | bmatT(+4718592)   (all 128B-aligned)
    char* ws = (char*)d_ws;
    int*   counts = (int*)ws;
    int*   ilist  = (int*)(ws + 128);
    int*   jlist  = (int*)(ws + 128 + 36864);
    unsigned long long* amax = (unsigned long long*)(ws + 128 + 2 * 36864);      // 147456 B
    float* amatT  = (float*)(ws + 128 + 2 * 36864 + 147456);                     // 4718592 B
    float* bmatT  = (float*)(ws + 128 + 2 * 36864 + 147456 + 4718592);           // 4718592 B

    // 1) compaction
    compact_kernel<<<1, 256, 0, stream>>>(mask, ilist, jlist, counts);
    // 2) transposed compacted A + normalized B (+ amax zeroing)
    buildab_kernel<<<(4 * HW + 255) / 256, 256, 0, stream>>>(x, ilist, jlist, counts,
                                                             amatT, bmatT, amax);
    // 3) tiled GEMM + argmax: grid (i-tiles, j-chunks, batch)
    {
        dim3 grid(HW / 64, NJC, 2);                  // dead i-tiles exit early
        gemm_argmax_kernel<<<grid, 256, 0, stream>>>(amatT, bmatT, ilist, counts, amax);
    }
    // 4) fused copy + decode + gather
    {
        int n = 2 * 192 * (HW / 4);
        epilogue_kernel<<<(n + 255) / 256, 256, 0, stream>>>((const float4*)x, x, mask, amax, jlist, out4);
    }
}